// Round 9
// baseline (1074.919 us; speedup 1.0000x reference)
//
#include <hip/hip_runtime.h>

#define BB 8
#define NN 4096
#define DD 64
#define SS 1024
#define KK 32
#define R2 0.04f

typedef float f32x2 __attribute__((ext_vector_type(2)));

// One DPP max stage: wv = max(wv, lanes-shifted wv). old = self -> invalid lanes
// contribute identity. row_shr:1,2,4,8 + row_bcast:15,31 -> lane 63 has wave max.
#define DPP_MAXF(wv, CTRL)                                                             \
    {                                                                                  \
        int _o = __builtin_amdgcn_update_dpp(__float_as_int(wv), __float_as_int(wv),   \
                                             CTRL, 0xf, 0xf, false);                   \
        (wv) = fmaxf((wv), __int_as_float(_o));                                        \
    }

// Redundant-FPS design: 256 blocks x 512 thr, one per CU (static LDS 81952 B >
// 81920 forces 1 block/CU). Block handles batch b = blk>>5 and chunk cs =
// blk&31: runs FPS for its batch up to step cs*32+32 (identical, deterministic,
// replicated work), then serves its own 32 groups from its own LDS. NO
// cross-block synchronization exists.
//
// R9 (informed by the full R2..R8 ledger: every ADDITION to the B0 step lost;
// the dominant unattacked serial term is the 8-wave barrier arrival/skew +
// same-address atomic drain): FPS now runs on TWO waves (32 pts/lane, coords
// and dist entirely in registers), synchronized per step by a version-tagged
// LDS slot pair + spin-poll — NO __syncthreads and NO atomics inside the loop.
// Waves 2-7 park inside the single post-FPS s_barrier (zero issue, unlike
// R7's spinning spectators). Slot u64 = (t+1)<<52 | valbits<<20 | (4095-g):
// equal tags make the low 52 bits order by (max val, then min index) — the
// replicated blocks get bit-identical winners (pure function, no races).
// Double-buffered slots (t&1) are race-free: wave A overwrites its parity-P
// slot at t+2 only after reading the peer's t+1 value, which the peer wrote
// after finishing its own t-step reads of parity P.
// Exactness: in-lane (val,idx) TREE picks smallest j on ties (left-preferred,
// layout ascending); ballot picks smallest lane (= smallest g, lane-major
// layout); cross-wave u64 picks max val then smallest global g — exactly the
// reference's first-argmax. Distance math and serve phase are byte-identical
// to the verified B0 kernel.
__global__ __launch_bounds__(512, 2) void fused_kernel(const float* __restrict__ xyz,
                                                       const float* __restrict__ points,
                                                       float* __restrict__ out) {
#pragma clang fp contract(off)
    __shared__ float4 sxyz[NN];                    // 65536 B {x,y,z,pad}
    __shared__ int sfar[SS];                       // 4096 B FPS index history
    __shared__ int bbuf[8][KK];                    // 1024 B per-wave ball lists
    volatile __shared__ unsigned long long slot[2][2];  // 32 B dbuf'd per-wave slots
    __shared__ unsigned long long lpad[1408];      // 11264 B LDS occupancy pad (live)
    // total 65536+4096+1024+32+11264 = 81952 B > 81920 => 1 block/CU guaranteed

    const int tid  = threadIdx.x;
    const int wave = tid >> 6;
    const int lane = tid & 63;
    const int b    = blockIdx.x >> 5;              // batch
    const int cs   = blockIdx.x & 31;              // group chunk within batch
    const float* xb = xyz + (size_t)b * NN * 3;
    const float* pb = points + (size_t)b * NN * DD;

    if (tid == 0) {                                // zero slot tags (tag 0 != any t+1)
        slot[0][0] = 0ull; slot[0][1] = 0ull; slot[1][0] = 0ull; slot[1][1] = 0ull;
    }
    for (int i = tid; i < 1408; i += 512) lpad[i] = 0ull;   // touch pad: keep allocated

    // ---- staging: 96 contiguous bytes per lane (8 points x 3 floats), 6x float4 ----
    {
        const float4* xb4 = (const float4*)(xb + tid * 24);
        const float4 q0 = xb4[0], q1 = xb4[1], q2 = xb4[2];
        const float4 q3 = xb4[3], q4 = xb4[4], q5 = xb4[5];
        float sx[8], sy[8], sz[8];
        sx[0] = q0.x; sy[0] = q0.y; sz[0] = q0.z;
        sx[1] = q0.w; sy[1] = q1.x; sz[1] = q1.y;
        sx[2] = q1.z; sy[2] = q1.w; sz[2] = q2.x;
        sx[3] = q2.y; sy[3] = q2.z; sz[3] = q2.w;
        sx[4] = q3.x; sy[4] = q3.y; sz[4] = q3.z;
        sx[5] = q3.w; sy[5] = q4.x; sz[5] = q4.y;
        sx[6] = q4.z; sy[6] = q4.w; sz[6] = q5.x;
        sx[7] = q5.y; sy[7] = q5.z; sz[7] = q5.w;
#pragma unroll
        for (int j = 0; j < 8; ++j)
            sxyz[tid * 8 + j] = make_float4(sx[j], sy[j], sz[j], 0.0f);
    }
    __syncthreads();                               // barrier #1: staging + inits visible

    const int tmax = cs * 32 + 32;                 // this block only needs sfar[0..tmax)

    // ================= FPS: waves 0,1 only; zero barriers, zero atomics =================
    if (wave < 2) {
        // lane owns 32 points, global idx g = wave*2048 + lane*32 + j (lane-major)
        const int base = (wave << 11) + lane * 32;
        f32x2 px[16], py[16], pz[16], dist[16];
#pragma unroll
        for (int u = 0; u < 16; ++u) {
            const float4 p0 = sxyz[base + 2 * u];
            const float4 p1 = sxyz[base + 2 * u + 1];
            px[u] = (f32x2){p0.x, p1.x};
            py[u] = (f32x2){p0.y, p1.y};
            pz[u] = (f32x2){p0.z, p1.z};
            dist[u] = (f32x2){1e10f, 1e10f};
        }
        int far = (int)(unsigned)lpad[0];          // == 0; keeps lpad live

        for (int t = 0; t < tmax; ++t) {
            if (tid == 0) sfar[t] = far;           // scan emits pre-update carry
            const float4 c = sxyz[far];            // one ds_read_b128 (broadcast)
            const f32x2 cx2 = (f32x2){c.x, c.x}, cy2 = (f32x2){c.y, c.y},
                        cz2 = (f32x2){c.z, c.z};

#pragma unroll
            for (int u = 0; u < 16; ++u) {
                // exact ref order: ((dx^2 + dy^2) + dz^2); contract(off) => no FMA
                const f32x2 dx = px[u] - cx2;
                const f32x2 dy = py[u] - cy2;
                const f32x2 dz = pz[u] - cz2;
                const f32x2 d  = (dx * dx + dy * dy) + dz * dz;
                f32x2 m;
                m.x = fminf(dist[u].x, d.x);       // fmin exact; order-independent
                m.y = fminf(dist[u].y, d.y);
                dist[u] = m;
            }
            // in-lane (val, idx) argmax TREE over 32 values: smallest j on ties
            // (left-preferred; "x == max" includes the equal case). Static idx only.
            float v1[16]; int g1[16];
#pragma unroll
            for (int u = 0; u < 16; ++u) {
                v1[u] = fmaxf(dist[u].x, dist[u].y);
                g1[u] = (dist[u].x == v1[u]) ? (2 * u) : (2 * u + 1);
            }
            float v2[8]; int g2[8];
#pragma unroll
            for (int u = 0; u < 8; ++u) {
                v2[u] = fmaxf(v1[2 * u], v1[2 * u + 1]);
                g2[u] = (v1[2 * u] == v2[u]) ? g1[2 * u] : g1[2 * u + 1];
            }
            float v3[4]; int g3[4];
#pragma unroll
            for (int u = 0; u < 4; ++u) {
                v3[u] = fmaxf(v2[2 * u], v2[2 * u + 1]);
                g3[u] = (v2[2 * u] == v3[u]) ? g2[2 * u] : g2[2 * u + 1];
            }
            float v4[2]; int g4[2];
#pragma unroll
            for (int u = 0; u < 2; ++u) {
                v4[u] = fmaxf(v3[2 * u], v3[2 * u + 1]);
                g4[u] = (v3[2 * u] == v4[u]) ? g3[2 * u] : g3[2 * u + 1];
            }
            const float bestv = fmaxf(v4[0], v4[1]);
            const int bestg = base + ((v4[0] == bestv) ? g4[0] : g4[1]);

            // wave max via fused DPP f32 max; smallest tying lane = smallest g
            float wv = bestv;
            DPP_MAXF(wv, 0x111);   // row_shr:1
            DPP_MAXF(wv, 0x112);   // row_shr:2
            DPP_MAXF(wv, 0x114);   // row_shr:4
            DPP_MAXF(wv, 0x118);   // row_shr:8
            DPP_MAXF(wv, 0x142);   // row_bcast:15
            DPP_MAXF(wv, 0x143);   // row_bcast:31
            const float maxw =
                __int_as_float(__builtin_amdgcn_readlane(__float_as_int(wv), 63));
            const unsigned long long hits = __ballot(bestv == maxw);
            const int L = __ffsll(hits) - 1;
            const int gW = __builtin_amdgcn_readlane(bestg, L);   // wave winner idx

            // spin exchange: write my slot, poll the peer's, combine in-register
            const unsigned long long mine =
                ((unsigned long long)(unsigned)(t + 1) << 52) |
                ((unsigned long long)__float_as_uint(maxw) << 20) |
                (unsigned long long)(unsigned)(4095 - gW);
            if (lane == 0) slot[t & 1][wave] = mine;              // ds_write_b64
            unsigned long long peer;
            do {                                                  // fresh volatile read
                peer = slot[t & 1][1 - wave];
            } while ((unsigned)(peer >> 52) != (unsigned)(t + 1));

            const unsigned long long M52 = (1ull << 52) - 1ull;
            unsigned long long best = mine & M52;
            const unsigned long long pl = peer & M52;
            if (pl > best) best = pl;                             // (max val, min g)
            far = 4095 - (int)(best & 0xFFFull);                  // next centroid
        }
    }
    __syncthreads();       // barrier #2: waves 2-7 park here (zero issue) during FPS;
                           // implies lgkmcnt(0) drain => sfar[] fully visible to all.

    // ============ this block's 32 groups: ball query + output, all from LDS ============
#pragma unroll
    for (int i = 0; i < 4; ++i) {
        const int s  = cs * 32 + wave * 4 + i;     // group within batch (s < tmax)
        const int g  = b * SS + s;                 // flat group id
        const int qi = sfar[s];
        const float4 q = sxyz[qi];
        const float qn = __fadd_rn(__fadd_rn(__fmul_rn(q.x, q.x), __fmul_rn(q.y, q.y)),
                                   __fmul_rn(q.z, q.z));

        int total = 0;
        for (int base2 = 0; base2 < NN && total < KK; base2 += 64) {
            const int n = base2 + lane;
            const float4 p = sxyz[n];              // ds_read_b128; values == global xyz
            const float pn = __fadd_rn(__fadd_rn(__fmul_rn(p.x, p.x), __fmul_rn(p.y, p.y)),
                                       __fmul_rn(p.z, p.z));
            const float dt = __fadd_rn(__fadd_rn(__fmul_rn(q.x, p.x), __fmul_rn(q.y, p.y)),
                                       __fmul_rn(q.z, p.z));
            // exact ref order: d = (-2*dot) + |q|^2 + |p|^2
            const float d = __fadd_rn(__fadd_rn(__fmul_rn(-2.0f, dt), qn), pn);
            const bool hit = !(d > R2);            // include iff d <= r^2
            const unsigned long long mask = __ballot(hit);
            const int before = __popcll(mask & ((1ull << lane) - 1ull));
            const int pos = total + before;
            if (hit && pos < KK) bbuf[wave][pos] = n;
            total += (int)__popcll(mask);
        }
        // pad with first element (wave-synchronous LDS, no barrier needed)
        if (lane < KK) {
            const int v = (lane < total) ? bbuf[wave][lane] : bbuf[wave][0];
            bbuf[wave][lane] = v;
        }

        // new_xyz
        if (lane < 3)
            out[(size_t)g * 3 + lane] = (lane == 0) ? q.x : (lane == 1) ? q.y : q.z;

        // anchor feature columns this lane is responsible for (same for all k)
        const float a1 = (lane >= 3) ? pb[qi * DD + (lane - 3)] : 0.0f;  // cols 67..127
        const float a2 = (lane < 3) ? pb[qi * DD + (61 + lane)] : 0.0f;  // cols 128..130

        float* outp = out + (size_t)BB * SS * 3 + (size_t)g * (KK * 131);
        for (int k = 0; k < KK; ++k) {
            const int idx = bbuf[wave][k];
            const float4 pi = sxyz[idx];
            outp[k * 131 + lane] = pb[idx * DD + lane];                    // cols 0..63
            const float v1c = (lane == 0) ? pi.x
                            : (lane == 1) ? pi.y
                            : (lane == 2) ? pi.z
                                          : a1;                            // cols 64..127
            outp[k * 131 + 64 + lane] = v1c;
            if (lane < 3) outp[k * 131 + 128 + lane] = a2;                 // cols 128..130
        }
    }
}

extern "C" void kernel_launch(void* const* d_in, const int* in_sizes, int n_in,
                              void* d_out, int out_size, void* d_ws, size_t ws_size,
                              hipStream_t stream) {
    const float* xyz    = (const float*)d_in[0];   // [B,N,3]
    const float* points = (const float*)d_in[1];   // [B,N,D]
    float* out = (float*)d_out;

    fused_kernel<<<BB * 32, 512, 0, stream>>>(xyz, points, out);
}

// Round 10
// 722.826 us; speedup vs baseline: 1.4871x; 1.4871x over previous
//
#include <hip/hip_runtime.h>

#define BB 8
#define NN 4096
#define DD 64
#define SS 1024
#define KK 32
#define R2 0.04f

typedef float f32x2 __attribute__((ext_vector_type(2)));

// One DPP max stage: wv = max(wv, lanes-shifted wv). old = self -> invalid lanes
// contribute identity. row_shr:1,2,4,8 + row_bcast:15,31 -> lane 63 has wave max.
#define DPP_MAXF(wv, CTRL)                                                             \
    {                                                                                  \
        int _o = __builtin_amdgcn_update_dpp(__float_as_int(wv), __float_as_int(wv),   \
                                             CTRL, 0xf, 0xf, false);                   \
        (wv) = fmaxf((wv), __int_as_float(_o));                                        \
    }

// Redundant-FPS design: 256 blocks x 512 thr, one per CU (static LDS 82176 B >
// 160KiB/2 forces 1 block/CU in hardware). Block handles batch b = blk>>5 and
// group chunk cs = blk&31: it computes the FPS for its batch up to step
// tmax = cs*32+32 (identical, deterministic work replicated across the 32
// blocks of that batch — fminf and max are order-independent, LDS atomicMax
// result is order-invariant), then serves its own 32 groups (ball query +
// output) entirely from its own LDS. NO cross-block synchronization exists.
//
// SESSION LEDGER (R2..R9, all measured on MI355X): this B0 step structure
// (pre-barrier same-address atomicMax exchange; post-barrier red[t] b64
// broadcast -> sxyz[far] b128 broadcast; 8 waves x 8 pts/lane) beat SEVEN
// structural variants: 5-word DPP butterfly (+251 us), lean 2-word butterfly
// (+97), coord-slot+readlane chain-shortening (+210), 4-wave specialization
// (+108), inline-asm packed math (+35), 2-wave spin-poll barrier-free (+334).
// Measured lesson: waves are barrier-locked to the same phase, so step time is
// the SUM of serial segments; every added op costs ~5 effective cycles and no
// latency-hiding exists at 2 waves/SIMD. Do not add ops to this loop.
// The only delta vs the verified 739us baseline is the early-exit tmax
// (critical block cs=31 executes the identical 1024-step stream; other blocks
// do strictly less work and stagger their output writes off the tail).
__global__ __launch_bounds__(512) void fused_kernel(const float* __restrict__ xyz,
                                                    const float* __restrict__ points,
                                                    float* __restrict__ out) {
#pragma clang fp contract(off)
    __shared__ float4 sxyz[NN];                    // 64 KB {x,y,z,pad}
    __shared__ unsigned long long red[SS + 416];   // 11.25 KB (416 = LDS occupancy pad)
    __shared__ int sfar[SS];                       // 4 KB
    __shared__ int bbuf[8][KK];                    // 1 KB per-wave ball lists

    const int tid  = threadIdx.x;
    const int wave = tid >> 6;
    const int lane = tid & 63;
    const int b    = blockIdx.x >> 5;              // batch
    const int cs   = blockIdx.x & 31;              // group chunk within batch
    const float* xb = xyz + (size_t)b * NN * 3;
    const float* pb = points + (size_t)b * NN * DD;

    for (int i = tid; i < SS; i += 512) red[i] = 0ull;   // slots: zero once

    // ---- init: 96 contiguous bytes per lane (8 points x 3 floats) via 6x float4 ----
    const float4* xb4 = (const float4*)(xb + tid * 24);
    const float4 q0 = xb4[0], q1 = xb4[1], q2 = xb4[2];
    const float4 q3 = xb4[3], q4 = xb4[4], q5 = xb4[5];

    f32x2 px[4], py[4], pz[4], dist[4];
    px[0] = (f32x2){q0.x, q0.w}; py[0] = (f32x2){q0.y, q1.x}; pz[0] = (f32x2){q0.z, q1.y};
    px[1] = (f32x2){q1.z, q2.y}; py[1] = (f32x2){q1.w, q2.z}; pz[1] = (f32x2){q2.x, q2.w};
    px[2] = (f32x2){q3.x, q3.w}; py[2] = (f32x2){q3.y, q4.x}; pz[2] = (f32x2){q3.z, q4.y};
    px[3] = (f32x2){q4.z, q5.y}; py[3] = (f32x2){q4.w, q5.z}; pz[3] = (f32x2){q5.x, q5.w};
#pragma unroll
    for (int jj = 0; jj < 4; ++jj) {
        const int i0 = tid * 8 + 2 * jj;
        sxyz[i0]     = make_float4(px[jj].x, py[jj].x, pz[jj].x, 0.0f);
        sxyz[i0 + 1] = make_float4(px[jj].y, py[jj].y, pz[jj].y, 0.0f);
        dist[jj] = (f32x2){1e10f, 1e10f};
    }
    __syncthreads();

    // ================= FPS (replicated per block; zero global ops) =================
    int far = 0;
    const int tmax = cs * 32 + 32;                 // this block only needs sfar[0..tmax)
    for (int t = 0; t < tmax; ++t) {
        if (tid == 0) sfar[t] = far;             // scan emits pre-update carry
        const float4 c = sxyz[far];              // one ds_read_b128 (broadcast)
        const f32x2 cx2 = (f32x2){c.x, c.x}, cy2 = (f32x2){c.y, c.y},
                    cz2 = (f32x2){c.z, c.z};

        f32x2 nd[4];
#pragma unroll
        for (int jj = 0; jj < 4; ++jj) {
            // exact ref order: ((dx^2 + dy^2) + dz^2); contract(off) => no FMA
            const f32x2 dx = px[jj] - cx2;
            const f32x2 dy = py[jj] - cy2;
            const f32x2 dz = pz[jj] - cz2;
            const f32x2 d  = (dx * dx + dy * dy) + dz * dz;
            f32x2 m;
            m.x = fminf(dist[jj].x, d.x);        // fmin exact; order-independent
            m.y = fminf(dist[jj].y, d.y);
            dist[jj] = m;
            nd[jj] = m;
        }
        // per-lane max (tree; values non-negative, no NaN)
        const float bestv =
            fmaxf(fmaxf(fmaxf(nd[0].x, nd[0].y), fmaxf(nd[1].x, nd[1].y)),
                  fmaxf(fmaxf(nd[2].x, nd[2].y), fmaxf(nd[3].x, nd[3].y)));
        // smallest j achieving it (descending scan => first match wins)
        int localj = 0;
#pragma unroll
        for (int j = 7; j >= 0; --j) {
            const float v = (j & 1) ? nd[j >> 1].y : nd[j >> 1].x;
            if (v == bestv) localj = j;
        }

        // wave max via fused DPP f32 max; recover first-lane index via ballot+ffs
        float wv = bestv;
        DPP_MAXF(wv, 0x111);   // row_shr:1
        DPP_MAXF(wv, 0x112);   // row_shr:2
        DPP_MAXF(wv, 0x114);   // row_shr:4
        DPP_MAXF(wv, 0x118);   // row_shr:8
        DPP_MAXF(wv, 0x142);   // row_bcast:15
        DPP_MAXF(wv, 0x143);   // row_bcast:31
        const float maxw =
            __int_as_float(__builtin_amdgcn_readlane(__float_as_int(wv), 63));

        const unsigned long long hits = __ballot(bestv == maxw);
        const int L = __ffsll(hits) - 1;         // smallest lane == smallest global idx
        const int candv = tid * 8 + localj;      // global point index
        const int cand  = __builtin_amdgcn_readlane(candv, L);

        // leaders race into the per-step slot; u64 max == (max val, min index);
        // final value is order-invariant => identical across replicated blocks
        if (lane == 0) {
            const unsigned long long p =
                ((unsigned long long)__float_as_uint(maxw) << 32) | (unsigned)(~cand);
            atomicMax(&red[t], p);
        }
        __syncthreads();                         // the only barrier in the step
        far = (int)(~(unsigned)red[t]);          // broadcast ds_read_b64
    }
    // sfar[] fully visible: each sfar[t] write precedes that step's barrier.

    // ============ this block's 32 groups: ball query + output, all from LDS ============
#pragma unroll
    for (int i = 0; i < 4; ++i) {
        const int s  = cs * 32 + wave * 4 + i;   // group within batch (s < tmax)
        const int g  = b * SS + s;               // flat group id
        const int qi = sfar[s];
        const float4 q = sxyz[qi];
        const float qn = __fadd_rn(__fadd_rn(__fmul_rn(q.x, q.x), __fmul_rn(q.y, q.y)),
                                   __fmul_rn(q.z, q.z));

        int total = 0;
        for (int base = 0; base < NN && total < KK; base += 64) {
            const int n = base + lane;
            const float4 p = sxyz[n];            // ds_read_b128; values == global xyz
            const float pn = __fadd_rn(__fadd_rn(__fmul_rn(p.x, p.x), __fmul_rn(p.y, p.y)),
                                       __fmul_rn(p.z, p.z));
            const float dt = __fadd_rn(__fadd_rn(__fmul_rn(q.x, p.x), __fmul_rn(q.y, p.y)),
                                       __fmul_rn(q.z, p.z));
            // exact ref order: d = (-2*dot) + |q|^2 + |p|^2
            const float d = __fadd_rn(__fadd_rn(__fmul_rn(-2.0f, dt), qn), pn);
            const bool hit = !(d > R2);          // include iff d <= r^2
            const unsigned long long mask = __ballot(hit);
            const int before = __popcll(mask & ((1ull << lane) - 1ull));
            const int pos = total + before;
            if (hit && pos < KK) bbuf[wave][pos] = n;
            total += (int)__popcll(mask);
        }
        // pad with first element (wave-synchronous LDS, no barrier needed)
        if (lane < KK) {
            const int v = (lane < total) ? bbuf[wave][lane] : bbuf[wave][0];
            bbuf[wave][lane] = v;
        }

        // new_xyz
        if (lane < 3)
            out[(size_t)g * 3 + lane] = (lane == 0) ? q.x : (lane == 1) ? q.y : q.z;

        // anchor feature columns this lane is responsible for (same for all k)
        const float a1 = (lane >= 3) ? pb[qi * DD + (lane - 3)] : 0.0f;  // cols 67..127
        const float a2 = (lane < 3) ? pb[qi * DD + (61 + lane)] : 0.0f;  // cols 128..130

        float* outp = out + (size_t)BB * SS * 3 + (size_t)g * (KK * 131);
        for (int k = 0; k < KK; ++k) {
            const int idx = bbuf[wave][k];
            const float4 pi = sxyz[idx];
            outp[k * 131 + lane] = pb[idx * DD + lane];                    // cols 0..63
            const float v1 = (lane == 0) ? pi.x
                           : (lane == 1) ? pi.y
                           : (lane == 2) ? pi.z
                                         : a1;                             // cols 64..127
            outp[k * 131 + 64 + lane] = v1;
            if (lane < 3) outp[k * 131 + 128 + lane] = a2;                 // cols 128..130
        }
    }
}

extern "C" void kernel_launch(void* const* d_in, const int* in_sizes, int n_in,
                              void* d_out, int out_size, void* d_ws, size_t ws_size,
                              hipStream_t stream) {
    const float* xyz    = (const float*)d_in[0];   // [B,N,3]
    const float* points = (const float*)d_in[1];   // [B,N,D]
    float* out = (float*)d_out;

    fused_kernel<<<BB * 32, 512, 0, stream>>>(xyz, points, out);
}

// Round 11
// 712.268 us; speedup vs baseline: 1.5092x; 1.0148x over previous
//
#include <hip/hip_runtime.h>

#define BB 8
#define NN 4096
#define DD 64
#define SS 1024
#define KK 32
#define R2 0.04f

typedef float f32x2 __attribute__((ext_vector_type(2)));

// One DPP max stage: wv = max(wv, lanes-shifted wv). old = self -> invalid lanes
// contribute identity. row_shr:1,2,4,8 + row_bcast:15,31 -> lane 63 has wave max.
#define DPP_MAXF(wv, CTRL)                                                             \
    {                                                                                  \
        int _o = __builtin_amdgcn_update_dpp(__float_as_int(wv), __float_as_int(wv),   \
                                             CTRL, 0xf, 0xf, false);                   \
        (wv) = fmaxf((wv), __int_as_float(_o));                                        \
    }

// Redundant-FPS design: 256 blocks x 512 thr, one per CU (static LDS 82176 B >
// 160KiB/2 forces 1 block/CU in hardware). Block handles batch b = blk>>5 and
// group chunk cs = blk&31: it computes the FPS for its batch up to step
// tmax = cs*32+32 (identical, deterministic work replicated across the 32
// blocks of that batch — fminf and max are order-independent, LDS atomicMax
// result is order-invariant), then serves its own 32 groups (ball query +
// output) entirely from its own LDS. NO cross-block synchronization exists.
//
// SESSION LEDGER (R2..R10, all measured on MI355X): this B0 step structure
// (pre-barrier same-address atomicMax exchange; post-barrier red[t] b64
// broadcast -> sxyz[far] b128 broadcast; 8 waves x 8 pts/lane) beat SEVEN
// structural variants: 5-word DPP butterfly (+251 us), lean 2-word butterfly
// (+97), coord-slot+readlane chain-shortening (+210), 4-wave specialization
// (+108), inline-asm packed math (+35), 2-wave spin-poll barrier-free (+334).
// Measured lesson: waves are barrier-locked to the same phase, so step time is
// the SUM of serial segments; additions lose, only REMOVALS win. R10 (this
// structure + early-exit tmax) measured 722.8us bench / ~636us dispatch — the
// session best. R11's single change is another pure removal: the per-step
// sfar[] write (divergent branch + ds_write in every step) is deleted; the
// serve phase derives qi = ~red[s-1] directly (far(0)=0), off the hot loop.
__global__ __launch_bounds__(512) void fused_kernel(const float* __restrict__ xyz,
                                                    const float* __restrict__ points,
                                                    float* __restrict__ out) {
#pragma clang fp contract(off)
    __shared__ float4 sxyz[NN];                    // 64 KB {x,y,z,pad}
    __shared__ unsigned long long red[SS + 928];   // 15.25 KB (928 = LDS occupancy pad;
                                                   //  absorbs the removed sfar's 4 KB)
    __shared__ int bbuf[8][KK];                    // 1 KB per-wave ball lists
    // total 65536 + 15616 + 1024 = 82176 B (same as R10) => 1 block/CU

    const int tid  = threadIdx.x;
    const int wave = tid >> 6;
    const int lane = tid & 63;
    const int b    = blockIdx.x >> 5;              // batch
    const int cs   = blockIdx.x & 31;              // group chunk within batch
    const float* xb = xyz + (size_t)b * NN * 3;
    const float* pb = points + (size_t)b * NN * DD;

    for (int i = tid; i < SS; i += 512) red[i] = 0ull;   // slots: zero once

    // ---- init: 96 contiguous bytes per lane (8 points x 3 floats) via 6x float4 ----
    const float4* xb4 = (const float4*)(xb + tid * 24);
    const float4 q0 = xb4[0], q1 = xb4[1], q2 = xb4[2];
    const float4 q3 = xb4[3], q4 = xb4[4], q5 = xb4[5];

    f32x2 px[4], py[4], pz[4], dist[4];
    px[0] = (f32x2){q0.x, q0.w}; py[0] = (f32x2){q0.y, q1.x}; pz[0] = (f32x2){q0.z, q1.y};
    px[1] = (f32x2){q1.z, q2.y}; py[1] = (f32x2){q1.w, q2.z}; pz[1] = (f32x2){q2.x, q2.w};
    px[2] = (f32x2){q3.x, q3.w}; py[2] = (f32x2){q3.y, q4.x}; pz[2] = (f32x2){q3.z, q4.y};
    px[3] = (f32x2){q4.z, q5.y}; py[3] = (f32x2){q4.w, q5.z}; pz[3] = (f32x2){q5.x, q5.w};
#pragma unroll
    for (int jj = 0; jj < 4; ++jj) {
        const int i0 = tid * 8 + 2 * jj;
        sxyz[i0]     = make_float4(px[jj].x, py[jj].x, pz[jj].x, 0.0f);
        sxyz[i0 + 1] = make_float4(px[jj].y, py[jj].y, pz[jj].y, 0.0f);
        dist[jj] = (f32x2){1e10f, 1e10f};
    }
    __syncthreads();

    // ================= FPS (replicated per block; zero global ops) =================
    int far = 0;
    const int tmax = cs * 32 + 32;                 // this block only needs steps < tmax
    for (int t = 0; t < tmax; ++t) {
        const float4 c = sxyz[far];              // one ds_read_b128 (broadcast)
        const f32x2 cx2 = (f32x2){c.x, c.x}, cy2 = (f32x2){c.y, c.y},
                    cz2 = (f32x2){c.z, c.z};

        f32x2 nd[4];
#pragma unroll
        for (int jj = 0; jj < 4; ++jj) {
            // exact ref order: ((dx^2 + dy^2) + dz^2); contract(off) => no FMA
            const f32x2 dx = px[jj] - cx2;
            const f32x2 dy = py[jj] - cy2;
            const f32x2 dz = pz[jj] - cz2;
            const f32x2 d  = (dx * dx + dy * dy) + dz * dz;
            f32x2 m;
            m.x = fminf(dist[jj].x, d.x);        // fmin exact; order-independent
            m.y = fminf(dist[jj].y, d.y);
            dist[jj] = m;
            nd[jj] = m;
        }
        // per-lane max (tree; values non-negative, no NaN)
        const float bestv =
            fmaxf(fmaxf(fmaxf(nd[0].x, nd[0].y), fmaxf(nd[1].x, nd[1].y)),
                  fmaxf(fmaxf(nd[2].x, nd[2].y), fmaxf(nd[3].x, nd[3].y)));
        // smallest j achieving it (descending scan => first match wins); runs in
        // parallel with the DPP reduce below (independent), off the serial chain
        int localj = 0;
#pragma unroll
        for (int j = 7; j >= 0; --j) {
            const float v = (j & 1) ? nd[j >> 1].y : nd[j >> 1].x;
            if (v == bestv) localj = j;
        }

        // wave max via fused DPP f32 max; recover first-lane index via ballot+ffs
        float wv = bestv;
        DPP_MAXF(wv, 0x111);   // row_shr:1
        DPP_MAXF(wv, 0x112);   // row_shr:2
        DPP_MAXF(wv, 0x114);   // row_shr:4
        DPP_MAXF(wv, 0x118);   // row_shr:8
        DPP_MAXF(wv, 0x142);   // row_bcast:15
        DPP_MAXF(wv, 0x143);   // row_bcast:31
        const float maxw =
            __int_as_float(__builtin_amdgcn_readlane(__float_as_int(wv), 63));

        const unsigned long long hits = __ballot(bestv == maxw);
        const int L = __ffsll(hits) - 1;         // smallest lane == smallest global idx
        const int candv = tid * 8 + localj;      // global point index
        const int cand  = __builtin_amdgcn_readlane(candv, L);

        // leaders race into the per-step slot; u64 max == (max val, min index);
        // final value is order-invariant => identical across replicated blocks
        if (lane == 0) {
            const unsigned long long p =
                ((unsigned long long)__float_as_uint(maxw) << 32) | (unsigned)(~cand);
            atomicMax(&red[t], p);
        }
        __syncthreads();                         // the only barrier in the step
        far = (int)(~(unsigned)red[t]);          // broadcast ds_read_b64
    }
    // red[0..tmax) finalized: every contribution precedes that step's barrier.

    // ============ this block's 32 groups: ball query + output, all from LDS ============
#pragma unroll
    for (int i = 0; i < 4; ++i) {
        const int s  = cs * 32 + wave * 4 + i;   // group within batch (s < tmax)
        const int g  = b * SS + s;               // flat group id
        // centroid index: the FPS scan emits the pre-update carry, i.e. the winner
        // of step s-1 (and index 0 for s==0) — read once, off the hot loop
        const int qi = (s == 0) ? 0 : (int)~(unsigned)red[s - 1];
        const float4 q = sxyz[qi];
        const float qn = __fadd_rn(__fadd_rn(__fmul_rn(q.x, q.x), __fmul_rn(q.y, q.y)),
                                   __fmul_rn(q.z, q.z));

        int total = 0;
        for (int base = 0; base < NN && total < KK; base += 64) {
            const int n = base + lane;
            const float4 p = sxyz[n];            // ds_read_b128; values == global xyz
            const float pn = __fadd_rn(__fadd_rn(__fmul_rn(p.x, p.x), __fmul_rn(p.y, p.y)),
                                       __fmul_rn(p.z, p.z));
            const float dt = __fadd_rn(__fadd_rn(__fmul_rn(q.x, p.x), __fmul_rn(q.y, p.y)),
                                       __fmul_rn(q.z, p.z));
            // exact ref order: d = (-2*dot) + |q|^2 + |p|^2
            const float d = __fadd_rn(__fadd_rn(__fmul_rn(-2.0f, dt), qn), pn);
            const bool hit = !(d > R2);          // include iff d <= r^2
            const unsigned long long mask = __ballot(hit);
            const int before = __popcll(mask & ((1ull << lane) - 1ull));
            const int pos = total + before;
            if (hit && pos < KK) bbuf[wave][pos] = n;
            total += (int)__popcll(mask);
        }
        // pad with first element (wave-synchronous LDS, no barrier needed)
        if (lane < KK) {
            const int v = (lane < total) ? bbuf[wave][lane] : bbuf[wave][0];
            bbuf[wave][lane] = v;
        }

        // new_xyz
        if (lane < 3)
            out[(size_t)g * 3 + lane] = (lane == 0) ? q.x : (lane == 1) ? q.y : q.z;

        // anchor feature columns this lane is responsible for (same for all k)
        const float a1 = (lane >= 3) ? pb[qi * DD + (lane - 3)] : 0.0f;  // cols 67..127
        const float a2 = (lane < 3) ? pb[qi * DD + (61 + lane)] : 0.0f;  // cols 128..130

        float* outp = out + (size_t)BB * SS * 3 + (size_t)g * (KK * 131);
        for (int k = 0; k < KK; ++k) {
            const int idx = bbuf[wave][k];
            const float4 pi = sxyz[idx];
            outp[k * 131 + lane] = pb[idx * DD + lane];                    // cols 0..63
            const float v1 = (lane == 0) ? pi.x
                           : (lane == 1) ? pi.y
                           : (lane == 2) ? pi.z
                                         : a1;                             // cols 64..127
            outp[k * 131 + 64 + lane] = v1;
            if (lane < 3) outp[k * 131 + 128 + lane] = a2;                 // cols 128..130
        }
    }
}

extern "C" void kernel_launch(void* const* d_in, const int* in_sizes, int n_in,
                              void* d_out, int out_size, void* d_ws, size_t ws_size,
                              hipStream_t stream) {
    const float* xyz    = (const float*)d_in[0];   // [B,N,3]
    const float* points = (const float*)d_in[1];   // [B,N,D]
    float* out = (float*)d_out;

    fused_kernel<<<BB * 32, 512, 0, stream>>>(xyz, points, out);
}